// Round 5
// baseline (46.620 us; speedup 1.0000x reference)
//
#include <hip/hip_runtime.h>

typedef float v2f __attribute__((ext_vector_type(2)));

#define Q_MIN 0.5f
#define MAXK 512
#define KHALF 256
#define BLK 256
#define GSC 128
#define NBM 1024
#define MAXN 131072

struct alignas(64) HitRec { float4 c0, c1, c2; float4 pad; };
// c0 = x[0..3], c1 = x[4..7], c2 = {-|x|^2, q_i, yi_bits, 0}

struct alignas(16) PlainRec { float a[8]; float u; float q; float p0, p1; };  // 48B
struct alignas(16) PairRec2 { float c[20]; };  // halves interleaved: (k, k+256)

struct Scratch {
  unsigned long long blk_packed[GSC][MAXK];
  unsigned int blk_fc[GSC][MAXK];
  PairRec2 tab2[KHALF];
  PlainRec plain[MAXK];
  float fcenterf[MAXK];
  float partial_lv[NBM];
  float partial_bkg[GSC];
  float partial_cnt[GSC];
  HitRec recs[MAXN];
};

__device__ __forceinline__ v2f bc2(float s) { return (v2f){s, s}; }

// scatter (LDS-atomic argmax + segment-max) + hit-record prep + bkg partials
__global__ void __launch_bounds__(BLK) k_scatprep(
    const float* __restrict__ x, const float* __restrict__ f,
    const int* __restrict__ y, const int* __restrict__ ei, const int* __restrict__ ej,
    int n, int e, Scratch* __restrict__ ws) {
  __shared__ unsigned long long sp[MAXK];
  __shared__ unsigned int sf[MAXK];
  for (int t = threadIdx.x; t < MAXK; t += BLK) { sp[t] = 0ull; sf[t] = 0u; }
  __syncthreads();
  float bk = 0.f, ct = 0.f;
  int nmax = n > e ? n : e;
  for (int t = blockIdx.x * BLK + threadIdx.x; t < nmax; t += GSC * BLK) {
    if (t < n) {
      int yi = y[t];
      float fv = f[t];
      float a = atanhf(fv);
      float q = fmaf(a, a, Q_MIN);
      const float4* xp = (const float4*)(x + (size_t)t * 8);
      float4 v0 = xp[0], v1 = xp[1];
      float x2 = v0.x*v0.x + v0.y*v0.y + v0.z*v0.z + v0.w*v0.w
               + v1.x*v1.x + v1.y*v1.y + v1.z*v1.z + v1.w*v1.w;
      if (t < MAXN) {
        HitRec* r = &ws->recs[t];
        r->c0 = v0; r->c1 = v1;
        r->c2 = make_float4(-x2, q, __int_as_float(yi), 0.f);
      }
      if (yi >= 0 && yi < MAXK) {
        unsigned long long p = ((unsigned long long)__float_as_uint(q) << 32)
                             | (unsigned long long)(0xFFFFFFFFu - (unsigned)t);
        atomicMax(&sp[yi], p);
      } else if (yi == -1) { bk += fv; ct += 1.f; }
    }
    if (t < e) {
      int j = ej[t];
      if (j >= 0 && j < MAXK)
        atomicMax(&sf[j], __float_as_uint(f[ei[t]]));  // f > 0: bits-max == fmax
    }
  }
  __syncthreads();
  for (int t = threadIdx.x; t < MAXK; t += BLK) {
    ws->blk_packed[blockIdx.x][t] = sp[t];
    ws->blk_fc[blockIdx.x][t] = sf[t];
  }
  for (int o = 32; o > 0; o >>= 1) { bk += __shfl_down(bk, o, 64); ct += __shfl_down(ct, o, 64); }
  __shared__ float rb[BLK / 64], rc[BLK / 64];
  int wid = threadIdx.x >> 6, lane = threadIdx.x & 63;
  if (lane == 0) { rb[wid] = bk; rc[wid] = ct; }
  __syncthreads();
  if (threadIdx.x == 0) {
    float sb = 0.f, sc = 0.f;
    #pragma unroll
    for (int w = 0; w < BLK / 64; ++w) { sb += rb[w]; sc += rc[w]; }
    ws->partial_bkg[blockIdx.x] = sb;
    ws->partial_cnt[blockIdx.x] = sc;
  }
}

// reduce per-block scatter tables; emit plain table + half-interleaved pair table
__global__ void __launch_bounds__(BLK) k_centers(
    const float* __restrict__ x, int n, Scratch* __restrict__ ws) {
  int t = blockIdx.x * BLK + threadIdx.x;
  if (t >= MAXK) return;
  unsigned long long m = 0ull;
  unsigned int fcb = 0u;
  for (int b = 0; b < GSC; ++b) {
    unsigned long long v = ws->blk_packed[b][t];
    m = v > m ? v : m;
    unsigned int w = ws->blk_fc[b][t];
    fcb = w > fcb ? w : fcb;
  }
  float q = 0.f, u = 0.f;
  float a[8];
  #pragma unroll
  for (int j = 0; j < 8; ++j) a[j] = 0.f;
  if (m != 0ull) {
    q = __uint_as_float((unsigned)(m >> 32));
    unsigned idx = 0xFFFFFFFFu - (unsigned)(m & 0xFFFFFFFFull);
    if (idx < (unsigned)n) {
      const float* xp = x + (size_t)idx * 8;
      float s2 = 0.f;
      #pragma unroll
      for (int j = 0; j < 8; ++j) { float v = xp[j]; s2 = fmaf(v, v, s2); a[j] = 2.f * v; }
      u = 1.f - s2;
    }
  }
  PlainRec* pr = &ws->plain[t];
  #pragma unroll
  for (int j = 0; j < 8; ++j) pr->a[j] = a[j];
  pr->u = u; pr->q = q; pr->p0 = 0.f; pr->p1 = 0.f;
  float* rec = (float*)&ws->tab2[t & (KHALF - 1)];
  int h = t >> 8;            // 0: k<256, 1: k>=256
  #pragma unroll
  for (int j = 0; j < 8; ++j) rec[2 * j + h] = a[j];
  rec[16 + h] = u;
  rec[18 + h] = q;
  ws->fcenterf[t] = __uint_as_float(fcb);
}

// transposed main loop: thread owns k and k+256 (table in VGPRs); blocks
// partition hits; hit records arrive via wave-uniform loads (scalar pipe).
__global__ void __launch_bounds__(BLK) k_main(
    const HitRec* __restrict__ recs, const PairRec2* __restrict__ tab2,
    const PlainRec* __restrict__ plain, float* __restrict__ partial_lv,
    int n, int hpb) {
  const float4* tp = (const float4*)&tab2[threadIdx.x];
  float4 t0 = tp[0], t1 = tp[1], t2 = tp[2], t3 = tp[3], t4 = tp[4];
  v2f a0 = {t0.x, t0.y}, a1 = {t0.z, t0.w}, a2 = {t1.x, t1.y}, a3 = {t1.z, t1.w};
  v2f a4 = {t2.x, t2.y}, a5 = {t2.z, t2.w}, a6 = {t3.x, t3.y}, a7 = {t3.z, t3.w};
  v2f u2 = {t4.x, t4.y}, q2 = {t4.z, t4.w};

  int i0 = blockIdx.x * hpb;
  int i1 = i0 + hpb;
  if (i1 > n) i1 = n;
  if (i1 > MAXN) i1 = MAXN;

  // phase 1: member-term fixup for this block's hit range (one term per hit)
  float fix = 0.f;
  for (int i = i0 + threadIdx.x; i < i1; i += BLK) {
    float4 c2 = recs[i].c2;
    int yi = __float_as_int(c2.z);
    if (yi >= 0 && yi < MAXK) {
      float4 h0 = recs[i].c0, h1 = recs[i].c1;
      const PlainRec* pr = &plain[yi];
      float r = pr->u + c2.x;
      r = fmaf(h0.x, pr->a[0], r); r = fmaf(h0.y, pr->a[1], r);
      r = fmaf(h0.z, pr->a[2], r); r = fmaf(h0.w, pr->a[3], r);
      r = fmaf(h1.x, pr->a[4], r); r = fmaf(h1.y, pr->a[5], r);
      r = fmaf(h1.z, pr->a[6], r); r = fmaf(h1.w, pr->a[7], r);
      float xinv = __builtin_amdgcn_fmed3f(r, 0.f, 1.f);
      float xd = fmaxf(1.f - r, 0.f);
      fix += (xd - xinv) * pr->q * c2.y;
    }
  }

  // phase 2: stream hits; 12 pk-f32 ops per thread per hit, zero LDS
  v2f acc = {0.f, 0.f};
  v2f zero2 = {0.f, 0.f}, one2 = {1.f, 1.f};
  #pragma unroll 4
  for (int i = i0; i < i1; ++i) {
    float4 h0 = recs[i].c0, h1 = recs[i].c1, h2 = recs[i].c2;  // wave-uniform
    v2f r = u2 + bc2(h2.x);
    r = __builtin_elementwise_fma(bc2(h0.x), a0, r);
    r = __builtin_elementwise_fma(bc2(h0.y), a1, r);
    r = __builtin_elementwise_fma(bc2(h0.z), a2, r);
    r = __builtin_elementwise_fma(bc2(h0.w), a3, r);
    r = __builtin_elementwise_fma(bc2(h1.x), a4, r);
    r = __builtin_elementwise_fma(bc2(h1.y), a5, r);
    r = __builtin_elementwise_fma(bc2(h1.z), a6, r);
    r = __builtin_elementwise_fma(bc2(h1.w), a7, r);
    v2f xinv = __builtin_elementwise_min(__builtin_elementwise_max(r, zero2), one2);
    acc = __builtin_elementwise_fma(xinv, bc2(h2.y), acc);
  }

  float lv = fmaf(acc[0], q2[0], fmaf(acc[1], q2[1], fix));
  for (int o = 32; o > 0; o >>= 1) lv += __shfl_down(lv, o, 64);
  __shared__ float rl[BLK / 64];
  int wid = threadIdx.x >> 6, lane = threadIdx.x & 63;
  if (lane == 0) rl[wid] = lv;
  __syncthreads();
  if (threadIdx.x == 0) {
    float s = 0.f;
    #pragma unroll
    for (int w = 0; w < BLK / 64; ++w) s += rl[w];
    partial_lv[blockIdx.x] = s;
  }
}

__global__ void __launch_bounds__(BLK) k_final(const int* __restrict__ kptr, int n,
    const Scratch* __restrict__ ws, float* __restrict__ out) {
  int K = kptr[0]; if (K > MAXK) K = MAXK;
  int tid = threadIdx.x;
  float a = 0.f, b = 0.f, c = 0.f, d = 0.f;
  for (int t = tid; t < NBM; t += BLK) a += ws->partial_lv[t];
  for (int t = tid; t < GSC; t += BLK) { b += ws->partial_bkg[t]; c += ws->partial_cnt[t]; }
  for (int t = tid; t < MAXK; t += BLK) d += ws->fcenterf[t];  // 0 for t >= K
  __shared__ float sa[BLK], sb[BLK], sc[BLK], sd[BLK];
  sa[tid] = a; sb[tid] = b; sc[tid] = c; sd[tid] = d;
  __syncthreads();
  for (int o = BLK / 2; o > 0; o >>= 1) {
    if (tid < o) {
      sa[tid] += sa[tid + o]; sb[tid] += sb[tid + o];
      sc[tid] += sc[tid + o]; sd[tid] += sd[tid + o];
    }
    __syncthreads();
  }
  if (tid == 0) {
    float b1 = 1.f - sd[0] / (float)K;
    float b2 = sb[0] / sc[0];            // S_B = 1
    out[0] = (b1 + b2) + sa[0] / (float)n;
  }
}

extern "C" void kernel_launch(void* const* d_in, const int* in_sizes, int n_in,
                              void* d_out, int out_size, void* d_ws, size_t ws_size,
                              hipStream_t stream) {
  const float* x = (const float*)d_in[0];
  const float* f = (const float*)d_in[1];
  const int*   y = (const int*)d_in[2];
  const int*  ei = (const int*)d_in[3];
  const int*  ej = (const int*)d_in[4];
  const int* kptr = (const int*)d_in[5];
  float* out = (float*)d_out;
  int n = in_sizes[1];
  int e = in_sizes[3];
  Scratch* ws = (Scratch*)d_ws;

  int hpb = (n + NBM - 1) / NBM;

  hipLaunchKernelGGL(k_scatprep, dim3(GSC),        dim3(BLK), 0, stream, x, f, y, ei, ej, n, e, ws);
  hipLaunchKernelGGL(k_centers,  dim3(MAXK / BLK), dim3(BLK), 0, stream, x, n, ws);
  hipLaunchKernelGGL(k_main,     dim3(NBM),        dim3(BLK), 0, stream,
                     ws->recs, ws->tab2, ws->plain, ws->partial_lv, n, hpb);
  hipLaunchKernelGGL(k_final,    dim3(1),          dim3(BLK), 0, stream, kptr, n, ws, out);
}